// Round 3
// baseline (6936.234 us; speedup 1.0000x reference)
//
#include <hip/hip_runtime.h>
#include <math.h>

// Problem constants (fixed by the reference)
#define HDIM   512
#define NDIM   16
#define SEQ    64
#define TSTEPS 63
#define BATCH  256
#define ODIM   9

// R2: decision-domain fix. The reference argmaxes the f32 SIGMOIDS, which
// saturate to exactly 1.0f for logits > ~17.3. Late decode steps have several
// saturated pointer logits simultaneously (ctx grows by repeated gathers), so
// np.argmax picks the FIRST saturated index while logit-argmax picks the
// largest logit -> deterministic flip (identical absmax across R0-f32/R1-f64).
// All discrete decisions now go through f32 sigmoid emulation of the numpy
// reference. Internals stay f64 (stream-bound kernel; f64 VALU ~free).
//
// Encoder S4 stack is dead code; only encoded = in_seq@in_W+in_b is needed,
// recomputed on the fly for the pointer gather.

__device__ __forceinline__ double gelu_exact(double x) {
    return 0.5 * x * (1.0 + erf(x * 0.70710678118654752440));
}

// f32 sigmoid exactly as numpy computes it: f32 logit, f32 exp, f32 divide.
__device__ __forceinline__ float sig32(double logit) {
    float x = (float)logit;
    return 1.0f / (1.0f + __expf(-x) * 0.0f + expf(-x));  // expf, no fast-math
}

// Block-wide sum over 512 threads (8 waves). All threads return the sum.
__device__ __forceinline__ double block_sum512d(double v, double* red, int tid) {
    #pragma unroll
    for (int m = 1; m < 64; m <<= 1) v += __shfl_xor(v, m);
    __syncthreads();                   // protect red[] reuse across calls
    if ((tid & 63) == 0) red[tid >> 6] = v;
    __syncthreads();
    return red[0] + red[1] + red[2] + red[3] + red[4] + red[5] + red[6] + red[7];
}

// Phase 1: diagonal-SSM state update + y reduction + gelu -> g[] in LDS.
// tid = hg*16 + n, hg in [0,32), n in [0,16). Thread owns h = hg + 32*k.
__device__ __forceinline__ void s4_state_g(
    double (&s)[16],
    const float (&Ar)[16], const float (&Br)[16], const float (&Cr)[16],
    const float* __restrict__ Dptr,        // D + j*HDIM
    const double* __restrict__ xd,         // LDS, block input (512)
    double* __restrict__ g,                // LDS, gelu output (512)
    int hg, int n)
{
    #pragma unroll
    for (int k = 0; k < 16; ++k) {
        int h = hg + 32 * k;
        double xh = xd[h];                 // broadcast within 16-lane group
        double sv = fma((double)Ar[k], s[k], (double)Br[k] * xh);
        s[k] = sv;
        double p = sv * (double)Cr[k];
        p += __shfl_xor(p, 1);
        p += __shfl_xor(p, 2);
        p += __shfl_xor(p, 4);
        p += __shfl_xor(p, 8);             // sum over n within 16-lane group
        if (n == 0) {
            double y = p + (double)Dptr[h] * xh;
            g[h] = gelu_exact(y);
        }
    }
}

// Phase 2: z[c] = sum_h g[h] * W[h][c]. Thread t -> (hq=t>>7, cq=t&127).
// Coalesced float4 weight stream from L2; f64 accumulate.
__device__ __forceinline__ void matvec512(
    const float* __restrict__ W,           // outW + j*HDIM*HDIM, [h][c]
    const double* __restrict__ g,          // LDS (512)
    double* __restrict__ zpart,            // LDS (4*512)
    int tid)
{
    int hq = tid >> 7;
    int cq = tid & 127;
    const float4* W4 = (const float4*)W;
    double ax = 0.0, ay = 0.0, az = 0.0, aw = 0.0;
    int hbeg = hq * 128;
    #pragma unroll 4
    for (int h = hbeg; h < hbeg + 128; ++h) {
        double gv = g[h];
        float4 w = W4[h * 128 + cq];
        ax = fma(gv, (double)w.x, ax);
        ay = fma(gv, (double)w.y, ay);
        az = fma(gv, (double)w.z, az);
        aw = fma(gv, (double)w.w, aw);
    }
    int base = hq * HDIM + 4 * cq;
    zpart[base]     = ax;
    zpart[base + 1] = ay;
    zpart[base + 2] = az;
    zpart[base + 3] = aw;
}

// Head: logits[o] = sum_h (xd[h]+ctx[h]) * headW[h][o] + headb[o]
__device__ __forceinline__ void head_logits(
    const double* __restrict__ xd, double ctxr,
    const float* __restrict__ headW, const float* __restrict__ headb,
    double* __restrict__ red,              // LDS >= 72 doubles
    double* __restrict__ logit,            // LDS >= 9 doubles
    int tid)
{
    double v = xd[tid] + ctxr;
    const float* w = headW + tid * ODIM;
    double p[ODIM];
    #pragma unroll
    for (int o = 0; o < ODIM; ++o) p[o] = v * (double)w[o];
    #pragma unroll
    for (int m = 1; m < 64; m <<= 1) {
        #pragma unroll
        for (int o = 0; o < ODIM; ++o) p[o] += __shfl_xor(p[o], m);
    }
    __syncthreads();
    if ((tid & 63) == 0) {
        int wv = tid >> 6;
        #pragma unroll
        for (int o = 0; o < ODIM; ++o) red[wv * ODIM + o] = p[o];
    }
    __syncthreads();
    if (tid < ODIM) {
        double s = (double)headb[tid];
        #pragma unroll
        for (int wv = 0; wv < 8; ++wv) s += red[wv * ODIM + tid];
        logit[tid] = s;
    }
    __syncthreads();
}

__global__ __launch_bounds__(512, 1)
void s4_decode_kernel(
    const float* __restrict__ input_seq,   // (B,S,3)
    const float* __restrict__ in_W,        // (3,H)
    const float* __restrict__ in_b,        // (H)
    const float* __restrict__ Aarr,        // (L,H,N)
    const float* __restrict__ Barr,        // (L,H,N)
    const float* __restrict__ Carr,        // (L,H,N)
    const float* __restrict__ Darr,        // (L,H)
    const float* __restrict__ outW,        // (L,H,H)
    const float* __restrict__ outb,        // (L,H)
    const float* __restrict__ ln_g,        // (L,H)
    const float* __restrict__ ln_b,        // (L,H)
    const float* __restrict__ headW,       // (H,9)
    const float* __restrict__ headb,       // (9)
    float* __restrict__ out)               // (B,T,9)
{
    __shared__ double ld_xd[HDIM];
    __shared__ double ld_g[HDIM];
    __shared__ double ld_z[4 * HDIM];
    __shared__ double ld_red[8 * ODIM];
    __shared__ double ld_logit[ODIM + 1];
    __shared__ double ld_dec[4];
    __shared__ int    ld_ptr;

    const int b   = blockIdx.x;
    const int tid = threadIdx.x;
    const int hg  = tid >> 4;
    const int n   = tid & 15;

    // ---- persistent per-thread registers: f64 states + f32 SSM params ----
    double s0[16], s1[16];
    float A0[16], B0[16], C0[16], A1[16], B1[16], C1[16];
    #pragma unroll
    for (int k = 0; k < 16; ++k) {
        int h  = hg + 32 * k;
        int i0 = h * NDIM + n;
        int i1 = (HDIM + h) * NDIM + n;
        A0[k] = Aarr[i0]; B0[k] = Barr[i0]; C0[k] = Carr[i0];
        A1[k] = Aarr[i1]; B1[k] = Barr[i1]; C1[k] = Carr[i1];
        s0[k] = 0.0; s1[k] = 0.0;
    }

    // per-column constants (exact f32 inputs; widen at use)
    const double inb_t = (double)in_b[tid];
    const double w0 = (double)in_W[tid];
    const double w1 = (double)in_W[HDIM + tid];
    const double w2 = (double)in_W[2 * HDIM + tid];
    const double ob0 = (double)outb[tid], ob1 = (double)outb[HDIM + tid];
    const double lg0 = (double)ln_g[tid], lg1 = (double)ln_g[HDIM + tid];
    const double lb0 = (double)ln_b[tid], lb1 = (double)ln_b[HDIM + tid];

    double ctxr = 0.0;                     // ctx[tid] lives in a register
    if (tid == 0) { ld_dec[0] = 0.0; ld_dec[1] = 0.0; ld_dec[2] = 1.0; }
    __syncthreads();

    for (int i = 0; i < TSTEPS; ++i) {
        // ---- decoder input projection: dp = dec_in @ in_W + in_b ----
        double dpv = fma(ld_dec[0], w0, fma(ld_dec[1], w1, fma(ld_dec[2], w2, inb_t)));
        __syncthreads();                   // ld_dec consumed; safe to reuse LDS
        ld_xd[tid] = dpv;
        __syncthreads();

        // ================= block 0 =================
        s4_state_g(s0, A0, B0, C0, Darr, ld_xd, ld_g, hg, n);
        __syncthreads();
        matvec512(outW, ld_g, ld_z, tid);
        __syncthreads();
        {
            double z = ld_z[tid] + ld_z[HDIM + tid] + ld_z[2 * HDIM + tid]
                     + ld_z[3 * HDIM + tid] + ob0;
            double res = (i == 0) ? dpv : z;   // ref: residual=proj on step 0
            double tmp = z + res;
            double mu  = block_sum512d(tmp, ld_red, tid) * (1.0 / 512.0);
            double d   = tmp - mu;
            double var = block_sum512d(d * d, ld_red, tid) * (1.0 / 512.0);
            double xn  = d * rsqrt(var + 1e-5) * lg0 + lb0;
            __syncthreads();
            ld_xd[tid] = xn;
            __syncthreads();
        }

        // ================= block 1 =================
        s4_state_g(s1, A1, B1, C1, Darr + HDIM, ld_xd, ld_g, hg, n);
        __syncthreads();
        matvec512(outW + HDIM * HDIM, ld_g, ld_z, tid);
        __syncthreads();
        {
            double z = ld_z[tid] + ld_z[HDIM + tid] + ld_z[2 * HDIM + tid]
                     + ld_z[3 * HDIM + tid] + ob1;
            double res = (i == 0) ? dpv : z;
            double tmp = z + res;
            double mu  = block_sum512d(tmp, ld_red, tid) * (1.0 / 512.0);
            double d   = tmp - mu;
            double var = block_sum512d(d * d, ld_red, tid) * (1.0 / 512.0);
            double xn  = d * rsqrt(var + 1e-5) * lg1 + lb1;
            __syncthreads();
            ld_xd[tid] = xn;
            __syncthreads();
        }

        // ================= head / pointer / output =================
        head_logits(ld_xd, ctxr, headW, headb, ld_red, ld_logit, tid);

        const bool is_out = ((i & 1) == 0);
        if (is_out) {
            // ctx unchanged -> out == o_ptr
            if (tid < ODIM)
                out[(b * TSTEPS + i) * ODIM + tid] = sig32(ld_logit[tid]);
            if (tid == 0) {
                // np: next_char = (sigmoid_f32(logit0) > 0.5)
                double nc = (sig32(ld_logit[0]) > 0.5f) ? 1.0 : 0.0;
                ld_dec[0] = nc; ld_dec[1] = 1.0; ld_dec[2] = 0.0;
            }
            __syncthreads();
        } else {
            // ptr = np.argmax over f32 SIGMOIDS of logits[3:9] (first-max).
            // Sigmoids saturate/quantize in f32 -> NOT equivalent to logit
            // argmax; must compare the f32-rounded sigmoid values.
            if (tid == 0) {
                int best = 0; float bv = sig32(ld_logit[3]);
                #pragma unroll
                for (int o = 1; o < 6; ++o) {
                    float v2 = sig32(ld_logit[3 + o]);
                    if (v2 > bv) { bv = v2; best = o; }
                }
                ld_ptr = best;
                ld_dec[0] = 0.0; ld_dec[1] = 0.0; ld_dec[2] = 1.0;
            }
            __syncthreads();
            // ctx += encoded[b, ptr, :]  (= in_seq[b,ptr,:] @ in_W + in_b)
            {
                const float* iseq = input_seq + (b * SEQ + ld_ptr) * 3;
                double e0 = (double)iseq[0], e1 = (double)iseq[1], e2 = (double)iseq[2];
                ctxr += fma(e0, w0, fma(e1, w1, fma(e2, w2, inb_t)));
            }
            __syncthreads();
            head_logits(ld_xd, ctxr, headW, headb, ld_red, ld_logit, tid);
            if (tid < ODIM)
                out[(b * TSTEPS + i) * ODIM + tid] = sig32(ld_logit[tid]);
            __syncthreads();
        }
        __syncthreads();   // ld_logit consumed before next iteration overwrites
    }
}

extern "C" void kernel_launch(void* const* d_in, const int* in_sizes, int n_in,
                              void* d_out, int out_size, void* d_ws, size_t ws_size,
                              hipStream_t stream) {
    (void)in_sizes; (void)n_in; (void)d_ws; (void)ws_size; (void)out_size;
    const float* input_seq = (const float*)d_in[0];
    // d_in[1] = autoregressive_steps (scalar) -- T fixed at 63 by the model
    const float* in_W   = (const float*)d_in[2];
    const float* in_b   = (const float*)d_in[3];
    const float* Aarr   = (const float*)d_in[4];
    const float* Barr   = (const float*)d_in[5];
    const float* Carr   = (const float*)d_in[6];
    const float* Darr   = (const float*)d_in[7];
    const float* outW   = (const float*)d_in[8];
    const float* outb   = (const float*)d_in[9];
    const float* ln_g   = (const float*)d_in[10];
    const float* ln_b   = (const float*)d_in[11];
    const float* headW  = (const float*)d_in[12];
    const float* headb  = (const float*)d_in[13];
    float* out = (float*)d_out;

    s4_decode_kernel<<<BATCH, 512, 0, stream>>>(
        input_seq, in_W, in_b, Aarr, Barr, Carr, Darr,
        outW, outb, ln_g, ln_b, headW, headb, out);
}

// Round 4
// 1839.786 us; speedup vs baseline: 3.7701x; 3.7701x over previous
//
#include <hip/hip_runtime.h>
#include <math.h>

// Problem constants (fixed by the reference)
#define HDIM   512
#define NDIM   16
#define SEQ    64
#define TSTEPS 63
#define BATCH  256
#define ODIM   9

// R4: f32 internals + per-WG rotated weight stream + 8-deep float4 prefetch.
// R3 evidence: dur independent of occupancy/VALU; FETCH_SIZE=3.4GB (10% L2
// miss on a 2.3MB working set) -> L2-miss fill path is the limiter (32 CUs
// per XCD streaming the same lines in lockstep). Rotation de-correlates the
// streams; deep prefetch raises MLP; f32 cuts VALU and LDS traffic ~2x.
// Precision: R0(f32)==R1(f64) bit-identical and R3(f64) had zero decision
// flips vs np-f32 -> decision margins tolerate f32 internals. All discrete
// decisions still go through f32-sigmoid emulation of numpy (saturation!).
//
// Encoder S4 stack is dead code; only encoded = in_seq@in_W+in_b is needed,
// recomputed on the fly for the pointer gather.

__device__ __forceinline__ float gelu_f32(float x) {
    return 0.5f * x * (1.0f + erff(x * 0.70710678118654752440f));
}

// f32 sigmoid exactly as numpy computes it.
__device__ __forceinline__ float sig32(float x) {
    return 1.0f / (1.0f + expf(-x));
}

// Block-wide sum over 512 threads (8 waves). All threads return the sum.
__device__ __forceinline__ float block_sum512(float v, float* red, int tid) {
    #pragma unroll
    for (int m = 1; m < 64; m <<= 1) v += __shfl_xor(v, m);
    __syncthreads();                   // protect red[] reuse across calls
    if ((tid & 63) == 0) red[tid >> 6] = v;
    __syncthreads();
    return red[0] + red[1] + red[2] + red[3] + red[4] + red[5] + red[6] + red[7];
}

// Phase 1: diagonal-SSM state update + y reduction + gelu -> g[] in LDS.
// tid = hg*16 + n, hg in [0,32), n in [0,16). Thread owns h = hg + 32*k.
__device__ __forceinline__ void s4_state_g(
    float (&s)[16],
    const float (&Ar)[16], const float (&Br)[16], const float (&Cr)[16],
    const float* __restrict__ Dlds,        // LDS copy of D row (512)
    const float* __restrict__ xd,          // LDS, block input (512)
    float* __restrict__ g,                 // LDS, gelu output (512)
    int hg, int n)
{
    #pragma unroll
    for (int k = 0; k < 16; ++k) {
        int h = hg + 32 * k;
        float xh = xd[h];                  // broadcast within 16-lane group
        float sv = fmaf(Ar[k], s[k], Br[k] * xh);
        s[k] = sv;
        float p = sv * Cr[k];
        p += __shfl_xor(p, 1);
        p += __shfl_xor(p, 2);
        p += __shfl_xor(p, 4);
        p += __shfl_xor(p, 8);             // sum over n within 16-lane group
        if (n == 0) {
            float y = p + Dlds[h] * xh;
            g[h] = gelu_f32(y);
        }
    }
}

// Phase 2: z[c] = sum_h g[h] * W[h][c]. Thread t -> (hq=t>>7 in [0,4),
// cq=t&127). 8-deep double-buffered float4 pipeline; per-WG rotation of the
// row order so the 32 CUs of an XCD don't hammer the same L2 lines at once.
__device__ __forceinline__ void matvec512(
    const float* __restrict__ W,           // outW + j*HDIM*HDIM, [h][c]
    const float* __restrict__ g,           // LDS (512)
    float* __restrict__ zpart,             // LDS (4*512)
    int tid, int rot)
{
    const int hq   = tid >> 7;
    const int cq   = tid & 127;
    const int base = hq * 128;
    const float4* W4 = (const float4*)W;
    float4 buf[8], nxt[8];
    #pragma unroll
    for (int p = 0; p < 8; ++p)
        buf[p] = W4[(base + ((rot + p) & 127)) * 128 + cq];
    float a0 = 0.f, a1 = 0.f, a2 = 0.f, a3 = 0.f;
    #pragma unroll 1
    for (int blk = 0; blk < 16; ++blk) {
        const int nb = ((blk + 1) & 15) * 8;   // wraps: last prefetch harmless
        #pragma unroll
        for (int p = 0; p < 8; ++p)
            nxt[p] = W4[(base + ((rot + nb + p) & 127)) * 128 + cq];
        #pragma unroll
        for (int p = 0; p < 8; ++p) {
            int h = base + ((rot + blk * 8 + p) & 127);
            float gv = g[h];               // wave-uniform LDS broadcast
            float4 w = buf[p];
            a0 = fmaf(gv, w.x, a0);
            a1 = fmaf(gv, w.y, a1);
            a2 = fmaf(gv, w.z, a2);
            a3 = fmaf(gv, w.w, a3);
        }
        #pragma unroll
        for (int p = 0; p < 8; ++p) buf[p] = nxt[p];
    }
    *(float4*)&zpart[hq * HDIM + 4 * cq] = make_float4(a0, a1, a2, a3);
}

// Head: logits[o] = sum_h (xd[h]+ctx[h]) * headW[h][o] + headb[o]
__device__ __forceinline__ void head_logits(
    const float* __restrict__ xd, float ctxr,
    const float* __restrict__ headW, const float* __restrict__ headb,
    float* __restrict__ red,               // LDS >= 72 floats
    float* __restrict__ logit,             // LDS >= 9 floats
    int tid)
{
    float v = xd[tid] + ctxr;
    const float* w = headW + tid * ODIM;
    float p[ODIM];
    #pragma unroll
    for (int o = 0; o < ODIM; ++o) p[o] = v * w[o];
    #pragma unroll
    for (int m = 1; m < 64; m <<= 1) {
        #pragma unroll
        for (int o = 0; o < ODIM; ++o) p[o] += __shfl_xor(p[o], m);
    }
    __syncthreads();
    if ((tid & 63) == 0) {
        int wv = tid >> 6;
        #pragma unroll
        for (int o = 0; o < ODIM; ++o) red[wv * ODIM + o] = p[o];
    }
    __syncthreads();
    if (tid < ODIM) {
        float s = headb[tid];
        #pragma unroll
        for (int wv = 0; wv < 8; ++wv) s += red[wv * ODIM + tid];
        logit[tid] = s;
    }
    __syncthreads();
}

__global__ __launch_bounds__(512, 2)
void s4_decode_kernel(
    const float* __restrict__ input_seq,   // (B,S,3)
    const float* __restrict__ in_W,        // (3,H)
    const float* __restrict__ in_b,        // (H)
    const float* __restrict__ Aarr,        // (L,H,N)
    const float* __restrict__ Barr,        // (L,H,N)
    const float* __restrict__ Carr,        // (L,H,N)
    const float* __restrict__ Darr,        // (L,H)
    const float* __restrict__ outW,        // (L,H,H)
    const float* __restrict__ outb,        // (L,H)
    const float* __restrict__ ln_g,        // (L,H)
    const float* __restrict__ ln_b,        // (L,H)
    const float* __restrict__ headW,       // (H,9)
    const float* __restrict__ headb,       // (9)
    float* __restrict__ out)               // (B,T,9)
{
    __shared__ float ld_xd[HDIM];
    __shared__ float ld_g[HDIM];
    __shared__ float ld_z[4 * HDIM];
    __shared__ float ld_D0[HDIM];
    __shared__ float ld_D1[HDIM];
    __shared__ float ld_red[8 * ODIM];
    __shared__ float ld_logit[ODIM + 1];
    __shared__ float ld_dec[4];
    __shared__ int   ld_ptr;

    const int b   = blockIdx.x;
    const int tid = threadIdx.x;
    const int hg  = tid >> 4;
    const int n   = tid & 15;
    // rotation: spread same-XCD WGs (blockIdx = x mod 8) across the row space
    const int rot = (b * 37) & 127;

    // ---- persistent per-thread registers: f32 states + SSM params ----
    float s0[16], s1[16];
    float A0[16], B0[16], C0[16], A1[16], B1[16], C1[16];
    #pragma unroll
    for (int k = 0; k < 16; ++k) {
        int h  = hg + 32 * k;
        int i0 = h * NDIM + n;
        int i1 = (HDIM + h) * NDIM + n;
        A0[k] = Aarr[i0]; B0[k] = Barr[i0]; C0[k] = Carr[i0];
        A1[k] = Aarr[i1]; B1[k] = Barr[i1]; C1[k] = Carr[i1];
        s0[k] = 0.f; s1[k] = 0.f;
    }

    // per-column constants
    const float inb_t = in_b[tid];
    const float w0 = in_W[tid], w1 = in_W[HDIM + tid], w2 = in_W[2 * HDIM + tid];
    const float ob0 = outb[tid], ob1 = outb[HDIM + tid];
    const float lg0 = ln_g[tid], lg1 = ln_g[HDIM + tid];
    const float lb0 = ln_b[tid], lb1 = ln_b[HDIM + tid];

    ld_D0[tid] = Darr[tid];
    ld_D1[tid] = Darr[HDIM + tid];

    float ctxr = 0.f;                      // ctx[tid] lives in a register
    if (tid == 0) { ld_dec[0] = 0.f; ld_dec[1] = 0.f; ld_dec[2] = 1.f; }
    __syncthreads();

    for (int i = 0; i < TSTEPS; ++i) {
        // ---- decoder input projection: dp = dec_in @ in_W + in_b ----
        float dpv = fmaf(ld_dec[0], w0, fmaf(ld_dec[1], w1, fmaf(ld_dec[2], w2, inb_t)));
        __syncthreads();                   // ld_dec consumed
        ld_xd[tid] = dpv;
        __syncthreads();

        // ================= block 0 =================
        s4_state_g(s0, A0, B0, C0, ld_D0, ld_xd, ld_g, hg, n);
        __syncthreads();
        matvec512(outW, ld_g, ld_z, tid, rot);
        __syncthreads();
        {
            float z = ld_z[tid] + ld_z[HDIM + tid] + ld_z[2 * HDIM + tid]
                    + ld_z[3 * HDIM + tid] + ob0;
            float res = (i == 0) ? dpv : z;    // ref: residual=proj on step 0
            float tmp = z + res;
            float mu  = block_sum512(tmp, ld_red, tid) * (1.f / 512.f);
            float d   = tmp - mu;
            float var = block_sum512(d * d, ld_red, tid) * (1.f / 512.f);
            float xn  = d * rsqrtf(var + 1e-5f) * lg0 + lb0;
            __syncthreads();
            ld_xd[tid] = xn;
            __syncthreads();
        }

        // ================= block 1 =================
        s4_state_g(s1, A1, B1, C1, ld_D1, ld_xd, ld_g, hg, n);
        __syncthreads();
        matvec512(outW + HDIM * HDIM, ld_g, ld_z, tid, rot);
        __syncthreads();
        {
            float z = ld_z[tid] + ld_z[HDIM + tid] + ld_z[2 * HDIM + tid]
                    + ld_z[3 * HDIM + tid] + ob1;
            float res = (i == 0) ? dpv : z;
            float tmp = z + res;
            float mu  = block_sum512(tmp, ld_red, tid) * (1.f / 512.f);
            float d   = tmp - mu;
            float var = block_sum512(d * d, ld_red, tid) * (1.f / 512.f);
            float xn  = d * rsqrtf(var + 1e-5f) * lg1 + lb1;
            __syncthreads();
            ld_xd[tid] = xn;
            __syncthreads();
        }

        // ================= head / pointer / output =================
        head_logits(ld_xd, ctxr, headW, headb, ld_red, ld_logit, tid);

        const bool is_out = ((i & 1) == 0);
        if (is_out) {
            // ctx unchanged -> out == o_ptr
            if (tid < ODIM)
                out[(b * TSTEPS + i) * ODIM + tid] = sig32(ld_logit[tid]);
            if (tid == 0) {
                // np: next_char = (sigmoid_f32(logit0) > 0.5)
                float nc = (sig32(ld_logit[0]) > 0.5f) ? 1.f : 0.f;
                ld_dec[0] = nc; ld_dec[1] = 1.f; ld_dec[2] = 0.f;
            }
            __syncthreads();
        } else {
            // ptr = np.argmax over f32 SIGMOIDS of logits[3:9] (first-max).
            // Sigmoids saturate to exactly 1.0f -> must compare sigmoid
            // values, not logits.
            if (tid == 0) {
                int best = 0; float bv = sig32(ld_logit[3]);
                #pragma unroll
                for (int o = 1; o < 6; ++o) {
                    float v2 = sig32(ld_logit[3 + o]);
                    if (v2 > bv) { bv = v2; best = o; }
                }
                ld_ptr = best;
                ld_dec[0] = 0.f; ld_dec[1] = 0.f; ld_dec[2] = 1.f;
            }
            __syncthreads();
            // ctx += encoded[b, ptr, :]  (= in_seq[b,ptr,:] @ in_W + in_b)
            {
                const float* iseq = input_seq + (b * SEQ + ld_ptr) * 3;
                float e0 = iseq[0], e1 = iseq[1], e2 = iseq[2];
                ctxr += fmaf(e0, w0, fmaf(e1, w1, fmaf(e2, w2, inb_t)));
            }
            __syncthreads();
            head_logits(ld_xd, ctxr, headW, headb, ld_red, ld_logit, tid);
            if (tid < ODIM)
                out[(b * TSTEPS + i) * ODIM + tid] = sig32(ld_logit[tid]);
            __syncthreads();
        }
        __syncthreads();   // ld_logit consumed before next iteration overwrites
    }
}

extern "C" void kernel_launch(void* const* d_in, const int* in_sizes, int n_in,
                              void* d_out, int out_size, void* d_ws, size_t ws_size,
                              hipStream_t stream) {
    (void)in_sizes; (void)n_in; (void)d_ws; (void)ws_size; (void)out_size;
    const float* input_seq = (const float*)d_in[0];
    // d_in[1] = autoregressive_steps (scalar) -- T fixed at 63 by the model
    const float* in_W   = (const float*)d_in[2];
    const float* in_b   = (const float*)d_in[3];
    const float* Aarr   = (const float*)d_in[4];
    const float* Barr   = (const float*)d_in[5];
    const float* Carr   = (const float*)d_in[6];
    const float* Darr   = (const float*)d_in[7];
    const float* outW   = (const float*)d_in[8];
    const float* outb   = (const float*)d_in[9];
    const float* ln_g   = (const float*)d_in[10];
    const float* ln_b   = (const float*)d_in[11];
    const float* headW  = (const float*)d_in[12];
    const float* headb  = (const float*)d_in[13];
    float* out = (float*)d_out;

    s4_decode_kernel<<<BATCH, 512, 0, stream>>>(
        input_seq, in_W, in_b, Aarr, Barr, Carr, Darr,
        outW, outb, ln_g, ln_b, headW, headb, out);
}